// Round 15
// baseline (238.593 us; speedup 1.0000x reference)
//
#include <hip/hip_runtime.h>
#include <hip/hip_bf16.h>
#include <cmath>

#define DIM 512
#define HID 256
#define ROWS_PB 32       // rows per block (100000 = 3125 * 32, no tail)
#define NCHUNK 16        // K chunks of 32
#define CB 16384         // B chunk bytes: 32k * 256c * 2B

typedef __attribute__((ext_vector_type(8))) short short8;
typedef __attribute__((ext_vector_type(4))) float f32x4;
typedef __attribute__((ext_vector_type(16))) float f32x16;

__device__ __forceinline__ unsigned short f2bf(float f) {
  union { float f; unsigned u; } v; v.f = f;
  unsigned u = v.u;
  return (unsigned short)((u + 0x7FFFu + ((u >> 16) & 1u)) >> 16);
}

// Pre-swizzle W1 (fp32 [512,256] row-major) into bf16 fragment order:
// w1s[((k>>3)*HID + c)*8 + (k&7)]. K-chunk c (32 k's) is the contiguous
// 16 KB at byte offset c*16384 — a linear global_load_lds copy.
__global__ void w1_swz_kernel(const float* __restrict__ W1,
                              unsigned short* __restrict__ w1s) {
  int tid = blockIdx.x * blockDim.x + threadIdx.x;
  if (tid >= DIM * HID) return;
  int k = tid / HID;
  int c = tid - k * HID;
  w1s[(((k >> 3) * HID) + c) * 8 + (k & 7)] = f2bf(W1[tid]);
}

__device__ __forceinline__ short8 cvt8(const f32x4 p0, const f32x4 p1) {
  short8 r;
  r[0] = (short)f2bf(p0[0]); r[1] = (short)f2bf(p0[1]);
  r[2] = (short)f2bf(p0[2]); r[3] = (short)f2bf(p0[3]);
  r[4] = (short)f2bf(p1[0]); r[5] = (short)f2bf(p1[1]);
  r[6] = (short)f2bf(p1[2]); r[7] = (short)f2bf(p1[3]);
  return r;
}

// 4 waves / 32 rows. Wave w: src s=w&1, col-half h=w>>1; 32x32x16 MFMA.
// NO A-staging: global fp32 z is already in A-fragment order (lane=row l31,
// 8 consecutive floats per k-slice) — loaded straight to regs with 2-chunk
// lookahead, so HBM reads flow continuously through the K-loop.
// B staged via global_load_lds (R7 mechanics), double-buffered, T3-minimum
// loop: STAGE(c+1) -> ds_read+MFMA -> one __syncthreads per chunk.
// Logits: 32-lane shuffle reduce (R14-proven). Epilogue: re-read z from
// global (L2/L3-hot) in fp32, combine, store.
__global__ __launch_bounds__(256, 3) void fa_main_kernel(
    const float* __restrict__ z1, const float* __restrict__ z2,
    const unsigned short* __restrict__ w1s,
    const float* __restrict__ bias1, const float* __restrict__ W2,
    const float* __restrict__ bias2, float* __restrict__ out, int n) {
  __shared__ char Bs[2][CB];      // 32 KB double buffer
  __shared__ float xs2[4][32];    // partial logits [(s*2+h)][row]

  const int t = threadIdx.x;
  const int w = t >> 6;
  const int l = t & 63;
  const int l31 = l & 31, lhi = l >> 5;
  const int s = w & 1;   // source
  const int h = w >> 1;  // hid col-half
  const int row0 = blockIdx.x * ROWS_PB;
  const int myrow = row0 + l31;
  const bool rok = myrow < n;
  const float* zz = s ? z2 : z1;
  // A-fragment stream: chunk c, kslice ks -> 8 consecutive fp32 at
  // ap + c*32 + ks*16 (lane holds row l31, k's lhi*8..+8 of each 16-slice).
  const float* ap = zz + (size_t)myrow * DIM + (lhi << 3);
  const f32x4 zf4 = (f32x4){0.f, 0.f, 0.f, 0.f};

  auto STAGE = [&](int cc, int buf) {
    const char* gsrc = (const char*)w1s + cc * CB + l * 16;
    char* ldst = (char*)&Bs[buf][0];
#pragma unroll
    for (int r = 0; r < 4; ++r) {
      const int rr = w + r * 4;
      __builtin_amdgcn_global_load_lds(
          (const __attribute__((address_space(1))) void*)(gsrc + rr * 1024),
          (__attribute__((address_space(3))) void*)(ldst + rr * 1024), 16, 0,
          0);
    }
  };

  // Prologue: B[0] stage + A chunks 0,1 into the 2-deep register pipe.
  STAGE(0, 0);
  f32x4 pa0[2][2], pa1[2][2];  // [ks][piece], slots for even/odd chunks
#pragma unroll
  for (int ks = 0; ks < 2; ++ks) {
    const float* p0 = ap + (ks << 4);
    pa0[ks][0] = rok ? *(const f32x4*)(p0) : zf4;
    pa0[ks][1] = rok ? *(const f32x4*)(p0 + 4) : zf4;
    const float* p1 = ap + 32 + (ks << 4);
    pa1[ks][0] = rok ? *(const f32x4*)(p1) : zf4;
    pa1[ks][1] = rok ? *(const f32x4*)(p1 + 4) : zf4;
  }

  f32x16 acc[4];
#pragma unroll
  for (int g = 0; g < 4; ++g)
#pragma unroll
    for (int r = 0; r < 16; ++r) acc[g][r] = 0.f;

  const int bBase = ((h << 2) << 5) + l31;  // (h*4+g)*32 + l31, g via +g*32

  __syncthreads();  // B[0] + A[0..1] resident

  // K-loop: T3-minimum. cvt A[c]; STAGE(c+1); load A[c+2] into the slot
  // just consumed; 8 ds_reads + 8 MFMAs; one barrier.
#pragma unroll
  for (int c = 0; c < NCHUNK; ++c) {
    short8 af0, af1;
    if (c & 1) {
      af0 = cvt8(pa1[0][0], pa1[0][1]);
      af1 = cvt8(pa1[1][0], pa1[1][1]);
    } else {
      af0 = cvt8(pa0[0][0], pa0[0][1]);
      af1 = cvt8(pa0[1][0], pa0[1][1]);
    }
    if (c + 1 < NCHUNK) STAGE(c + 1, (c + 1) & 1);
    if (c + 2 < NCHUNK) {
      const float* apn = ap + ((c + 2) << 5);
      if (c & 1) {
#pragma unroll
        for (int ks = 0; ks < 2; ++ks) {
          pa1[ks][0] = rok ? *(const f32x4*)(apn + (ks << 4)) : zf4;
          pa1[ks][1] = rok ? *(const f32x4*)(apn + (ks << 4) + 4) : zf4;
        }
      } else {
#pragma unroll
        for (int ks = 0; ks < 2; ++ks) {
          pa0[ks][0] = rok ? *(const f32x4*)(apn + (ks << 4)) : zf4;
          pa0[ks][1] = rok ? *(const f32x4*)(apn + (ks << 4) + 4) : zf4;
        }
      }
    }
    __builtin_amdgcn_sched_barrier(0);  // pin loads above the compute
    const short8* bsc = (const short8*)&Bs[c & 1][0];
#pragma unroll
    for (int ks = 0; ks < 2; ++ks) {
      const short8 af = ks ? af1 : af0;
      const short8* bp = bsc + (((ks << 1) + lhi) << 8) + bBase;
#pragma unroll
      for (int g = 0; g < 4; ++g) {
        const short8 bf = bp[g << 5];
        acc[g] = __builtin_amdgcn_mfma_f32_32x32x16_bf16(af, bf, acc[g], 0, 0,
                                                         0);
      }
    }
    __syncthreads();  // drains STAGE(c+1); buffer swap safe
  }

  // Logits. C/D (32x32): col = (h*4+g)*32 + l31, row = (r&3)+8*(r>>2)+4*lhi.
  float part[16];
#pragma unroll
  for (int r = 0; r < 16; ++r) part[r] = 0.f;
#pragma unroll
  for (int g = 0; g < 4; ++g) {
    const int cc = ((h << 2) + g) * 32 + l31;
    const float w2v = W2[cc];
    const float b1v = bias1[cc];
#pragma unroll
    for (int r = 0; r < 16; ++r) {
      const float hh = acc[g][r] + b1v;
      part[r] += (hh > 0.f) ? hh * w2v : 0.f;
    }
  }
#pragma unroll
  for (int r = 0; r < 16; ++r) {
#pragma unroll
    for (int m = 1; m < 32; m <<= 1) part[r] += __shfl_xor(part[r], m, 64);
  }
  if (l31 == 0) {
#pragma unroll
    for (int r = 0; r < 16; ++r) {
      const int row = (r & 3) + ((r >> 2) << 3) + (lhi << 2);
      xs2[(s << 1) + h][row] = part[r];
    }
  }
  __syncthreads();

  // Epilogue: wave w covers rows w*8..w*8+8; lane l covers cols l*4 and
  // 256+l*4. z re-read from global (L2/L3-hot), fp32 end to end.
#pragma unroll
  for (int j = 0; j < 8; ++j) {
    const int rl = (w << 3) + j;
    const int grow = row0 + rl;
    if (grow < n) {
      const float x = xs2[0][rl] + xs2[1][rl];
      const float y = xs2[2][rl] + xs2[3][rl];
      const float sx = 1.f / (1.f + __expf(y - x));  // b2 cancels
      const float sy = 1.f - sx;
      const size_t off = (size_t)grow * DIM + (l << 2);
#pragma unroll
      for (int half = 0; half < 2; ++half) {
        const size_t o = off + (half << 8);
        const f32x4 a4 = *(const f32x4*)(z1 + o);
        const f32x4 b4 = *(const f32x4*)(z2 + o);
        f32x4 ov;
        ov[0] = sx * a4[0] + sy * b4[0];
        ov[1] = sx * a4[1] + sy * b4[1];
        ov[2] = sx * a4[2] + sy * b4[2];
        ov[3] = sx * a4[3] + sy * b4[3];
        *(f32x4*)(out + o) = ov;
      }
    }
  }
}

extern "C" void kernel_launch(void* const* d_in, const int* in_sizes, int n_in,
                              void* d_out, int out_size, void* d_ws,
                              size_t ws_size, hipStream_t stream) {
  const float* z1 = (const float*)d_in[0];
  const float* z2 = (const float*)d_in[1];
  const float* W1 = (const float*)d_in[2];
  const float* b1 = (const float*)d_in[3];
  const float* W2 = (const float*)d_in[4];
  const float* b2 = (const float*)d_in[5];
  float* out = (float*)d_out;
  const int n = in_sizes[0] / DIM;
  unsigned short* w1s = (unsigned short*)d_ws;  // 512*256*2 = 256 KB

  hipLaunchKernelGGL(w1_swz_kernel, dim3((DIM * HID + 255) / 256), dim3(256),
                     0, stream, W1, w1s);
  const int nwg = (n + ROWS_PB - 1) / ROWS_PB;
  hipLaunchKernelGGL(fa_main_kernel, dim3(nwg), dim3(256), 0, stream, z1, z2,
                     w1s, b1, W2, b2, out, n);
}